// Round 1
// baseline (1447.572 us; speedup 1.0000x reference)
//
#include <hip/hip_runtime.h>

#define IN_C 128
#define HID  64
#define NCLS 40
#define CHP  2048     // edges per scatter_part chunk (measured sweet spot)
#define SPT  512      // scatter_part threads
#define CHH  4096     // edges per bhist chunk
#define NB   1024     // padded bucket-array size (B <= 1024)
#define AGT  512      // aggregation threads (8 waves/block)

typedef float f32x4 __attribute__((ext_vector_type(4)));
typedef short s16x8 __attribute__((ext_vector_type(8)));

// ---- bf16 helpers: RTN pack ----
static __device__ inline unsigned short f2bf(float f) {
    unsigned u = __float_as_uint(f);
    return (unsigned short)((u + 0x7FFF + ((u >> 16) & 1)) >> 16);
}

// truncation split: v = hi + lo with hi = top-16-bit truncation
static __device__ inline void split1(float v, unsigned short& hb, unsigned short& lb) {
    hb = (unsigned short)(__float_as_uint(v) >> 16);
    float vhi = __uint_as_float((unsigned)hb << 16);
    lb = (unsigned short)(__float_as_uint(v - vhi) >> 16);
}

static __device__ inline void split8(const f32x4 a0, const f32x4 a1, s16x8& hi, s16x8& lo) {
    float v[8] = {a0.x, a0.y, a0.z, a0.w, a1.x, a1.y, a1.z, a1.w};
#pragma unroll
    for (int j = 0; j < 8; ++j) {
        unsigned short hb, lb;
        split1(v[j], hb, lb);
        hi[j] = (short)hb;
        lo[j] = (short)lb;
    }
}

// ===== bucket histogram + per-node degree (fused, one pass over dst) =======
// bcnt[b] = #edges with dst>>7 == b ;  deg[v] = in-degree of v

__global__ __launch_bounds__(256) void bhist_deg(
    const int* __restrict__ dst, int* __restrict__ bcnt, int* __restrict__ deg,
    int E, int B)
{
    __shared__ int h[NB];
    const int t = threadIdx.x;
    for (int i = t; i < NB; i += 256) h[i] = 0;
    __syncthreads();
    const int base = blockIdx.x * CHH;
    const int nE = min(CHH, E - base);
    for (int k = t; k < nE; k += 256) {
        int d = dst[base + k];
        atomicAdd(&h[d >> 7], 1);
        atomicAdd(&deg[d], 1);      // L2 hw atomic, deg fits L2
    }
    __syncthreads();
    for (int b = t; b < B; b += 256) { int c = h[b]; if (c) atomicAdd(&bcnt[b], c); }
}

// ================= bucket scan: bptr = exclusive scan(bcnt), bfill = copy ====

__global__ __launch_bounds__(256) void bscan_kernel(
    const int* __restrict__ bcnt, int* __restrict__ bptr, int* __restrict__ bfill,
    int B, int E)
{
    __shared__ int s[256];
    const int t = threadIdx.x;
    int v[4]; int ts = 0;
#pragma unroll
    for (int j = 0; j < 4; ++j) {
        int idx = 4 * t + j;
        v[j] = (idx < B) ? bcnt[idx] : 0;
        ts += v[j];
    }
    s[t] = ts; __syncthreads();
    for (int off = 1; off < 256; off <<= 1) {
        int add = (t >= off) ? s[t - off] : 0;
        __syncthreads();
        s[t] += add;
        __syncthreads();
    }
    int run = s[t] - ts;
#pragma unroll
    for (int j = 0; j < 4; ++j) {
        int idx = 4 * t + j;
        if (idx < B) { bptr[idx] = run; bfill[idx] = run; run += v[j]; }
    }
    if (t == 0) bptr[B] = E;
}

// ====== coarse partition: part[] = edges grouped by dst>>7 =================
// packed word = (src << 7) | (dst & 127).  512 threads: serial phases halved.

__global__ __launch_bounds__(SPT) void scatter_part(
    const int* __restrict__ src, const int* __restrict__ dst,
    int* __restrict__ bfill, int* __restrict__ part, int E, int B)
{
    __shared__ int cnt[NB], soff[NB], gpos[NB], sdata[SPT];
    __shared__ int stage[CHP], destg[CHP];
    const int t = threadIdx.x;
    const int base = blockIdx.x * CHP;
    const int nE = min(CHP, E - base);

    for (int i = t; i < NB; i += SPT) cnt[i] = 0;
    __syncthreads();
    // pass a: histogram by bucket
    for (int k = t; k < nE; k += SPT)
        atomicAdd(&cnt[dst[base + k] >> 7], 1);
    __syncthreads();
    // block-exclusive scan of cnt[0..NB) (thread t owns 2t, 2t+1)
    int v0 = cnt[2 * t], v1 = cnt[2 * t + 1];
    int ts = v0 + v1;
    sdata[t] = ts; __syncthreads();
    for (int off = 1; off < SPT; off <<= 1) {
        int add = (t >= off) ? sdata[t - off] : 0;
        __syncthreads();
        sdata[t] += add;
        __syncthreads();
    }
    int run = sdata[t] - ts;
    soff[2 * t] = run;
    soff[2 * t + 1] = run + v0;
    __syncthreads();
    // claim global runs (one atomic per non-empty (block,bucket))
    for (int b = t; b < B; b += SPT) {
        int c = cnt[b];
        gpos[b] = c ? atomicAdd(&bfill[b], c) : 0;
    }
    __syncthreads();
    for (int i = t; i < NB; i += SPT) cnt[i] = 0;   // reuse as cursor
    __syncthreads();
    // pass b: bin into LDS stage, record global destination
    for (int k = t; k < nE; k += SPT) {
        int d = dst[base + k];
        int b = d >> 7;
        int p = atomicAdd(&cnt[b], 1);
        int o = soff[b] + p;
        stage[o] = (src[base + k] << 7) | (d & 127);
        destg[o] = gpos[b] + p;
    }
    __syncthreads();
    // full-width copy: consecutive k within a run -> consecutive destinations
    for (int k = t; k < nE; k += SPT)
        part[destg[k]] = stage[k];
}

// ====== GEMM1 (MFMA): hs1b = bf16((x @ W1) * rsqrt(deg+1)) =================

__global__ __launch_bounds__(256) void gemm1_mfma(
    const float* __restrict__ x, const float* __restrict__ W1,
    const int* __restrict__ deg, unsigned short* __restrict__ hs1b, int n)
{
    const int wave = threadIdx.x >> 6;
    const int lane = threadIdx.x & 63;
    const int m    = lane & 15;
    const int q    = lane >> 4;
    const int col  = wave * 16 + m;

    s16x8 bhi[4], blo[4];
#pragma unroll
    for (int t = 0; t < 4; ++t) {
#pragma unroll
        for (int j = 0; j < 8; ++j) {
            int k = t * 32 + q * 8 + j;
            unsigned short hb, lb;
            split1(W1[k * HID + col], hb, lb);
            bhi[t][j] = (short)hb;
            blo[t][j] = (short)lb;
        }
    }

    const int nslab = n >> 4;
    for (int s = blockIdx.x; s < nslab; s += gridDim.x) {
        const float* xrow = x + (size_t)(s * 16 + m) * IN_C;
        f32x4 acc = {0.f, 0.f, 0.f, 0.f};
#pragma unroll
        for (int t = 0; t < 4; ++t) {
            f32x4 a0 = *(const f32x4*)(xrow + t * 32 + q * 8);
            f32x4 a1 = *(const f32x4*)(xrow + t * 32 + q * 8 + 4);
            s16x8 ahi, alo;
            split8(a0, a1, ahi, alo);
            acc = __builtin_amdgcn_mfma_f32_16x16x32_bf16(ahi, bhi[t], acc, 0, 0, 0);
            acc = __builtin_amdgcn_mfma_f32_16x16x32_bf16(alo, bhi[t], acc, 0, 0, 0);
            acc = __builtin_amdgcn_mfma_f32_16x16x32_bf16(ahi, blo[t], acc, 0, 0, 0);
        }
#pragma unroll
        for (int r = 0; r < 4; ++r) {
            int row = s * 16 + q * 4 + r;
            float dsc = rsqrtf((float)(deg[row] + 1));
            hs1b[(size_t)row * HID + col] = f2bf(acc[r] * dsc);
        }
    }
}

// ===== agg1 (bucket): LDS accumulate whole 128-node bucket =================
// One block per bucket, accum[128][64] f32 in LDS (32 KB), ds_add_f32 per msg.
// Edges come straight from part (packed (src<<7)|dstlocal); sentinel word
// (n<<7)|127 gathers the zeroed hs1b row n -> unconditional adds.
// Epilogue: h1 = relu((accum + self)*rsqrt(deg+1) + b1), packed bf16.

__global__ __launch_bounds__(AGT) void agg1_bucket(
    const int* __restrict__ bptr, const int* __restrict__ part,
    const int* __restrict__ deg, const unsigned* __restrict__ hs1p,
    const float* __restrict__ b1, unsigned* __restrict__ h1p, int n)
{
    __shared__ float accum[128 * 64];
    const int t = threadIdx.x;
    const int wave = t >> 6, lane = t & 63;
    const int h = lane >> 5, hl = lane & 31;
    const int base = blockIdx.x << 7;
    const int rstart = bptr[blockIdx.x], rend = bptr[blockIdx.x + 1];

    for (int i = t; i < 128 * 64; i += AGT) accum[i] = 0.f;
    __syncthreads();

    const int ZW = (n << 7) | 127;          // sentinel: src=n (zero row), dl=127
    for (int bb = rstart + wave * 64; bb < rend; bb += AGT) {
        int m = rend - bb; if (m > 64) m = 64;
        int myw = (lane < m) ? part[bb + lane] : ZW;
        int rounds = (m + 1) >> 1;          // 2 edges per round (h = half)
        for (int j = 0; j < rounds; j += 8) {
            unsigned w[8]; int dl[8];
#pragma unroll
            for (int u = 0; u < 8; ++u) {
                int wd = __shfl(myw, 2 * (j + u) + h);     // <= 63 always
                dl[u] = wd & 127;
                w[u] = hs1p[((unsigned)wd >> 7) * 32u + (unsigned)hl];
            }
#pragma unroll
            for (int u = 0; u < 8; ++u) {
                float* ap = &accum[dl[u] * 64 + 2 * hl];
                atomicAdd(ap,     __uint_as_float(w[u] << 16));
                atomicAdd(ap + 1, __uint_as_float(w[u] & 0xffff0000u));
            }
        }
    }
    __syncthreads();

    // epilogue: 128 rows x 32 u32 each, coalesced
    for (int idx = t; idx < 128 * 32; idx += AGT) {
        int nl = idx >> 5, c = idx & 31;
        int node = base + nl;
        if (node >= n) break;               // node monotone in idx per thread
        unsigned sw = hs1p[(unsigned)node * 32u + (unsigned)c];   // self-loop
        float d = rsqrtf((float)(deg[node] + 1));
        float v0 = (accum[nl * 64 + 2 * c]     + __uint_as_float(sw << 16))         * d + b1[2 * c];
        float v1 = (accum[nl * 64 + 2 * c + 1] + __uint_as_float(sw & 0xffff0000u)) * d + b1[2 * c + 1];
        v0 = v0 > 0.f ? v0 : 0.f;
        v1 = v1 > 0.f ? v1 : 0.f;
        h1p[(unsigned)node * 32u + (unsigned)c] = (unsigned)f2bf(v0) | ((unsigned)f2bf(v1) << 16);
    }
}

// ====== GEMM2 (MFMA): hs2b = bf16((h1 @ W2) * rsqrt(deg+1)), h1 native bf16

__global__ __launch_bounds__(192) void gemm2_mfma(
    const unsigned short* __restrict__ h1b, const float* __restrict__ W2,
    const int* __restrict__ deg, unsigned short* __restrict__ hs2b, int n)
{
    const int wave = threadIdx.x >> 6;
    const int lane = threadIdx.x & 63;
    const int m    = lane & 15;
    const int q    = lane >> 4;
    const int col  = wave * 16 + m;

    s16x8 bhi[2], blo[2];
#pragma unroll
    for (int t = 0; t < 2; ++t) {
#pragma unroll
        for (int j = 0; j < 8; ++j) {
            int k = t * 32 + q * 8 + j;
            float w = (col < NCLS) ? W2[k * NCLS + col] : 0.f;
            unsigned short hb, lb;
            split1(w, hb, lb);
            bhi[t][j] = (short)hb;
            blo[t][j] = (short)lb;
        }
    }

    const int nslab = n >> 4;
    for (int s = blockIdx.x; s < nslab; s += gridDim.x) {
        const unsigned short* hrow = h1b + (size_t)(s * 16 + m) * HID;
        f32x4 acc = {0.f, 0.f, 0.f, 0.f};
#pragma unroll
        for (int t = 0; t < 2; ++t) {
            s16x8 ahi = *(const s16x8*)(hrow + t * 32 + q * 8);   // native bf16 A
            acc = __builtin_amdgcn_mfma_f32_16x16x32_bf16(ahi, bhi[t], acc, 0, 0, 0);
            acc = __builtin_amdgcn_mfma_f32_16x16x32_bf16(ahi, blo[t], acc, 0, 0, 0);
        }
        if (col < NCLS) {
#pragma unroll
            for (int r = 0; r < 4; ++r) {
                int row = s * 16 + q * 4 + r;
                float dsc = rsqrtf((float)(deg[row] + 1));
                hs2b[(size_t)row * NCLS + col] = f2bf(acc[r] * dsc);
            }
        }
    }
}

// ===== agg2 (bucket): accum[128][40] f32 in LDS (20 KB) ====================
// row = 20 dwords. 3 edges/round, lane-group g=lane/20 takes edge 3j+g.
// g==3 lanes and out-of-range edges redirected to sentinel (zero row n, dl=127).
// Epilogue: out = (accum + self)*rsqrt(deg+1) + b2 (f32, float2 stores).

__global__ __launch_bounds__(AGT) void agg2_bucket(
    const int* __restrict__ bptr, const int* __restrict__ part,
    const int* __restrict__ deg, const unsigned* __restrict__ hs2p,
    const float* __restrict__ b2, float* __restrict__ out, int n)
{
    __shared__ float accum[128 * 40];
    const int t = threadIdx.x;
    const int wave = t >> 6, lane = t & 63;
    const int g  = lane / 20;          // edge-group 0..2 (3 = inactive)
    const int gl = lane - g * 20;      // dword within row
    const bool act = g < 3;
    const int base = blockIdx.x << 7;
    const int rstart = bptr[blockIdx.x], rend = bptr[blockIdx.x + 1];

    for (int i = t; i < 128 * 40; i += AGT) accum[i] = 0.f;
    __syncthreads();

    const int ZW = (n << 7) | 127;
    for (int bb = rstart + wave * 64; bb < rend; bb += AGT) {
        int m = rend - bb; if (m > 64) m = 64;
        int myw = (lane < m) ? part[bb + lane] : ZW;
        int j = 0;
        // full batches: 24 edges each, only g==3 needs the sentinel redirect
        for (; 24 * (j / 8 + 1) <= m; j += 8) {
            unsigned w[8]; int dl[8];
#pragma unroll
            for (int u = 0; u < 8; ++u) {
                int e = 3 * (j + u) + g;                  // < m <= 64 for act
                int wd = __shfl(myw, act ? e : 0);
                unsigned srow = act ? ((unsigned)wd >> 7) : (unsigned)n;
                dl[u] = act ? (wd & 127) : 127;
                w[u] = hs2p[srow * 20u + (unsigned)gl];
            }
#pragma unroll
            for (int u = 0; u < 8; ++u) {
                float* ap = &accum[dl[u] * 40 + 2 * gl];
                atomicAdd(ap,     __uint_as_float(w[u] << 16));
                atomicAdd(ap + 1, __uint_as_float(w[u] & 0xffff0000u));
            }
        }
        // tail batches: full validity redirect
        int rounds = (m + 2) / 3;
        for (; j < rounds; j += 8) {
            unsigned w[8]; int dl[8];
#pragma unroll
            for (int u = 0; u < 8; ++u) {
                int e = 3 * (j + u) + g;
                bool ok = act && (e < m);
                int wd = __shfl(myw, ok ? e : 0);
                unsigned srow = ok ? ((unsigned)wd >> 7) : (unsigned)n;
                dl[u] = ok ? (wd & 127) : 127;
                w[u] = hs2p[srow * 20u + (unsigned)gl];
            }
#pragma unroll
            for (int u = 0; u < 8; ++u) {
                float* ap = &accum[dl[u] * 40 + 2 * gl];
                atomicAdd(ap,     __uint_as_float(w[u] << 16));
                atomicAdd(ap + 1, __uint_as_float(w[u] & 0xffff0000u));
            }
        }
    }
    __syncthreads();

    // epilogue: 128 rows x 20 float2 each, coalesced
    for (int idx = t; idx < 128 * 20; idx += AGT) {
        int nl = idx / 20, c = idx - nl * 20;
        int node = base + nl;
        if (node >= n) break;
        unsigned sw = hs2p[(unsigned)node * 20u + (unsigned)c];   // self-loop
        float d = rsqrtf((float)(deg[node] + 1));
        float v0 = (accum[nl * 40 + 2 * c]     + __uint_as_float(sw << 16))         * d + b2[2 * c];
        float v1 = (accum[nl * 40 + 2 * c + 1] + __uint_as_float(sw & 0xffff0000u)) * d + b2[2 * c + 1];
        float2 vv; vv.x = v0; vv.y = v1;
        *(float2*)&out[(size_t)node * 40 + 2 * c] = vv;
    }
}

// ================= launch =================

extern "C" void kernel_launch(void* const* d_in, const int* in_sizes, int n_in,
                              void* d_out, int out_size, void* d_ws, size_t ws_size,
                              hipStream_t stream) {
    const float* x  = (const float*)d_in[0];
    const int*   ei = (const int*)d_in[1];
    const float* W1 = (const float*)d_in[2];
    const float* b1 = (const float*)d_in[3];
    const float* W2 = (const float*)d_in[4];
    const float* b2 = (const float*)d_in[5];
    float* out = (float*)d_out;

    const int n = in_sizes[0] / IN_C;        // 100000
    const int E = in_sizes[1] / 2;           // 1600000
    const int B = (n + 127) >> 7;            // 782 buckets of 128 nodes
    const int* src = ei;
    const int* dst = ei + E;

    char* ws = (char*)d_ws;
    size_t off = 0;
    auto alloc = [&](size_t bytes) { char* p = ws + off; off += (bytes + 255) & ~(size_t)255; return p; };
    int*   deg  = (int*)  alloc((size_t)n * 4);
    int*   bcnt = (int*)  alloc((size_t)NB * 4);
    int*   bptr = (int*)  alloc((size_t)(NB + 1) * 4);
    int*   bfill= (int*)  alloc((size_t)NB * 4);
    unsigned short* hs1b = (unsigned short*)alloc((size_t)(n + 1) * HID * 2);    // +1 zero row
    unsigned short* h1b  = (unsigned short*)alloc((size_t)n * HID * 2);
    unsigned short* hs2b = (unsigned short*)alloc((size_t)(n + 1) * NCLS * 2);   // +1 zero row
    int* part = (int*)alloc((size_t)E * 4);

    hipMemsetAsync(bcnt, 0, (size_t)B * 4, stream);
    hipMemsetAsync(deg, 0, (size_t)n * 4, stream);
    hipMemsetAsync(hs1b + (size_t)n * HID, 0, HID * 2, stream);    // zero sentinel row
    hipMemsetAsync(hs2b + (size_t)n * NCLS, 0, NCLS * 2, stream);  // zero sentinel row

    bhist_deg<<<(E + CHH - 1) / CHH, 256, 0, stream>>>(dst, bcnt, deg, E, B);
    bscan_kernel<<<1, 256, 0, stream>>>(bcnt, bptr, bfill, B, E);
    scatter_part<<<(E + CHP - 1) / CHP, SPT, 0, stream>>>(src, dst, bfill, part, E, B);

    gemm1_mfma<<<2048, 256, 0, stream>>>(x, W1, deg, hs1b, n);
    agg1_bucket<<<B, AGT, 0, stream>>>(bptr, part, deg, (const unsigned*)hs1b, b1,
                                       (unsigned*)h1b, n);
    gemm2_mfma<<<2048, 192, 0, stream>>>(h1b, W2, deg, hs2b, n);
    agg2_bucket<<<B, AGT, 0, stream>>>(bptr, part, deg, (const unsigned*)hs2b, b2,
                                       out, n);
}